// Round 1
// baseline (440.035 us; speedup 1.0000x reference)
//
#include <hip/hip_runtime.h>

#define NBINS 64

__global__ __launch_bounds__(256) void survemd_kernel(
    const float* __restrict__ y_hat,
    const int* __restrict__ t,
    const int* __restrict__ e,
    float* __restrict__ out,
    int n_rows)
{
    const int lane = threadIdx.x & 63;
    const int wave_in_block = threadIdx.x >> 6;
    const int waves_per_block = blockDim.x >> 6;
    const int wave_id = blockIdx.x * waves_per_block + wave_in_block;
    const int total_waves = gridDim.x * waves_per_block;

    const float s = 2.0611536224385579e-9f;   // exp(-20)
    float acc = 0.0f;

    for (int row = wave_id; row < n_rows; row += total_waves) {
        // force wave-uniform row -> scalar loads for t/e
        const int urow = __builtin_amdgcn_readfirstlane(row);
        const int tt = t[urow];
        const int ee = e[urow];

        const float y = y_hat[(size_t)urow * NBINS + lane];

        // pred: e==1 -> y_hat; e==0 -> (j>=t ? 10 : y_hat)
        const bool ge = (lane >= tt);
        const float pred = (ee == 0 && ge) ? 10.0f : y;
        float x = __expf(pred);   // no max-subtraction needed: pred <= 10

        // inclusive prefix scan across 64 lanes (gives cumsum AND total)
        #pragma unroll
        for (int off = 1; off < 64; off <<= 1) {
            float v = __shfl_up(x, off, 64);
            if (lane >= off) x += v;
        }
        const float total = __shfl(x, 63, 64);
        const float cps = x * __builtin_amdgcn_rcpf(total);

        // analytic cumsum of target_dist (softmax of +-10 logits)
        const float k = (ee == 1) ? 1.0f : (float)(NBINS - tt);
        const float rden = __builtin_amdgcn_rcpf(k + (64.0f - k) * s);
        const float hi = rden;
        const float lo = s * rden;
        const float ones = ge ? ((ee == 1) ? 1.0f : (float)(lane - tt + 1)) : 0.0f;
        const float cts = ones * hi + ((float)(lane + 1) - ones) * lo;

        const float d = cps - cts;
        acc = fmaf(d, d, acc);
    }

    // wave reduction of per-lane partials
    #pragma unroll
    for (int off = 32; off >= 1; off >>= 1)
        acc += __shfl_down(acc, off, 64);

    __shared__ float wave_sums[8];
    if (lane == 0) wave_sums[wave_in_block] = acc;
    __syncthreads();
    if (threadIdx.x == 0) {
        float bsum = 0.0f;
        for (int w = 0; w < waves_per_block; ++w) bsum += wave_sums[w];
        atomicAdd(out, bsum * (1.0f / (float)n_rows));
    }
}

extern "C" void kernel_launch(void* const* d_in, const int* in_sizes, int n_in,
                              void* d_out, int out_size, void* d_ws, size_t ws_size,
                              hipStream_t stream) {
    const float* y_hat = (const float*)d_in[0];
    const int*   t     = (const int*)d_in[1];
    const int*   e     = (const int*)d_in[2];
    float* out = (float*)d_out;

    const int n_rows = in_sizes[1];  // B

    // harness poisons d_out with 0xAA before every timed launch
    hipMemsetAsync(out, 0, out_size * sizeof(float), stream);

    const int block = 256;                 // 4 waves/block
    const int grid  = 8192;                // 32768 waves, 32 rows each
    survemd_kernel<<<grid, block, 0, stream>>>(y_hat, t, e, out, n_rows);
}

// Round 3
// 405.752 us; speedup vs baseline: 1.0845x; 1.0845x over previous
//
#include <hip/hip_runtime.h>

#define NBINS 64

// DPP row_shr:N add within 16-lane rows, 0-fill (bound_ctrl=1) -> scan step.
// CTRL must be a compile-time constant -> template parameter.
template <int CTRL>
__device__ __forceinline__ float dpp_shr_add(float x) {
    int xi = __float_as_int(x);
    int sh = __builtin_amdgcn_update_dpp(0, xi, CTRL, 0xF, 0xF, true);
    return x + __int_as_float(sh);
}

// Process 4 rows (one "quad") with one wave: lanes [seg*16, seg*16+15] handle
// row quad*4+seg; each lane holds 4 consecutive bins via one float4 load.
__device__ __forceinline__ float quad_rows(const float4* __restrict__ yv,
                                           const int* __restrict__ t,
                                           const int* __restrict__ e,
                                           int quad, int lane, int n_rows) {
    const int seg = lane >> 4;    // which of the 4 rows
    const int sl  = lane & 15;    // lane within the 16-lane segment
    const int row = quad * 4 + seg;
    const bool valid = row < n_rows;
    const int crow = valid ? row : (n_rows - 1);   // clamp for safe loads

    const int tt = t[crow];
    const int ee = e[crow];
    const float4 y = yv[(size_t)crow * (NBINS / 4) + sl];

    const int j0 = sl * 4;

    // pred: e==1 -> y ; e==0 -> (j>=t ? 10 : y). exp without max-subtraction
    // (pred <= 10, sum <= 64*e^10 ~ 1.4e6: safe in fp32).
    const bool cen = (ee == 0);
    const float x0 = __expf((cen && (j0 + 0 >= tt)) ? 10.0f : y.x);
    const float x1 = __expf((cen && (j0 + 1 >= tt)) ? 10.0f : y.y);
    const float x2 = __expf((cen && (j0 + 2 >= tt)) ? 10.0f : y.z);
    const float x3 = __expf((cen && (j0 + 3 >= tt)) ? 10.0f : y.w);

    // lane-local inclusive prefix of the 4 elements
    const float p0 = x0;
    const float p1 = p0 + x1;
    const float p2 = p1 + x2;
    const float p3 = p2 + x3;

    // 16-lane inclusive scan of the per-lane sums (pure VALU via DPP).
    // row_shr shifts within 16-lane DPP rows, so segments stay independent.
    float sc = p3;
    sc = dpp_shr_add<0x111>(sc);   // row_shr:1
    sc = dpp_shr_add<0x112>(sc);   // row_shr:2
    sc = dpp_shr_add<0x114>(sc);   // row_shr:4
    sc = dpp_shr_add<0x118>(sc);   // row_shr:8

    const float total = __shfl(sc, 15, 16);   // segment total (softmax denom)
    const float excl  = sc - p3;              // exclusive prefix for this lane
    const float rtot  = __builtin_amdgcn_rcpf(total);
    const float er    = excl * rtot;

    // analytic cumsum of target_dist (softmax of +-10 logits):
    // k = #(+10 logits); hi = 1/(k + (64-k)s); lo = s*hi; s = e^-20
    const float s = 2.0611536224385579e-9f;
    const float k  = (ee == 1) ? 1.0f : (float)(NBINS - tt);
    const float hi = __builtin_amdgcn_rcpf(k + (64.0f - k) * s);
    const float lo = s * hi;

    float acc = 0.0f;
    #pragma unroll
    for (int c = 0; c < 4; ++c) {
        const int j = j0 + c;
        const float p = (c == 0) ? p0 : (c == 1) ? p1 : (c == 2) ? p2 : p3;
        const float ones = (j >= tt) ? ((ee == 1) ? 1.0f : (float)(j - tt + 1))
                                     : 0.0f;
        const float cts = ones * hi + ((float)(j + 1) - ones) * lo;
        const float cps = fmaf(p, rtot, er);   // (excl + p) / total
        const float d = cps - cts;
        acc = fmaf(d, d, acc);
    }
    return valid ? acc : 0.0f;
}

__global__ __launch_bounds__(256) void survemd_kernel(
    const float* __restrict__ y_hat,
    const int* __restrict__ t,
    const int* __restrict__ e,
    float* __restrict__ out,
    int n_rows)
{
    const int lane = threadIdx.x & 63;
    const int wave_in_block = threadIdx.x >> 6;
    const int waves_per_block = blockDim.x >> 6;
    const int wave_id = blockIdx.x * waves_per_block + wave_in_block;
    const int total_waves = gridDim.x * waves_per_block;

    const float4* yv = (const float4*)y_hat;
    const int nquads = (n_rows + 3) >> 2;

    float acc = 0.0f;
    // 2 independent quads per iteration -> two overlapping dependency chains
    for (int q = wave_id; q < nquads; q += 2 * total_waves) {
        acc += quad_rows(yv, t, e, q, lane, n_rows);
        const int q2 = q + total_waves;
        if (q2 < nquads)
            acc += quad_rows(yv, t, e, q2, lane, n_rows);
    }

    // wave reduction
    #pragma unroll
    for (int off = 32; off >= 1; off >>= 1)
        acc += __shfl_down(acc, off, 64);

    __shared__ float wave_sums[8];
    if (lane == 0) wave_sums[wave_in_block] = acc;
    __syncthreads();
    if (threadIdx.x == 0) {
        float bsum = 0.0f;
        for (int w = 0; w < waves_per_block; ++w) bsum += wave_sums[w];
        atomicAdd(out, bsum * (1.0f / (float)n_rows));
    }
}

extern "C" void kernel_launch(void* const* d_in, const int* in_sizes, int n_in,
                              void* d_out, int out_size, void* d_ws, size_t ws_size,
                              hipStream_t stream) {
    const float* y_hat = (const float*)d_in[0];
    const int*   t     = (const int*)d_in[1];
    const int*   e     = (const int*)d_in[2];
    float* out = (float*)d_out;

    const int n_rows = in_sizes[1];  // B

    // harness poisons d_out with 0xAA before every timed launch
    (void)hipMemsetAsync(out, 0, out_size * sizeof(float), stream);

    const int block = 256;                 // 4 waves/block
    const int grid  = 8192;                // 32768 waves
    survemd_kernel<<<grid, block, 0, stream>>>(y_hat, t, e, out, n_rows);
}

// Round 4
// 385.081 us; speedup vs baseline: 1.1427x; 1.0537x over previous
//
#include <hip/hip_runtime.h>

#define NBINS 64

// DPP row_shr:N add within 16-lane rows, 0-fill (bound_ctrl=1) -> scan step.
template <int CTRL>
__device__ __forceinline__ float dpp_shr_add(float x) {
    int xi = __float_as_int(x);
    int sh = __builtin_amdgcn_update_dpp(0, xi, CTRL, 0xF, 0xF, true);
    return x + __int_as_float(sh);
}

// Compute the loss contribution for one quad (4 rows) from preloaded values.
// Lanes [seg*16 .. seg*16+15] handle one row; each lane holds 4 bins.
__device__ __forceinline__ float quad_compute(float4 y, int tt, int ee,
                                              int sl, bool valid) {
    const int j0 = sl * 4;

    // pred: e==1 -> y ; e==0 -> (j>=t ? 10 : y). exp safe without max-sub.
    const bool cen = (ee == 0);
    const float x0 = __expf((cen && (j0 + 0 >= tt)) ? 10.0f : y.x);
    const float x1 = __expf((cen && (j0 + 1 >= tt)) ? 10.0f : y.y);
    const float x2 = __expf((cen && (j0 + 2 >= tt)) ? 10.0f : y.z);
    const float x3 = __expf((cen && (j0 + 3 >= tt)) ? 10.0f : y.w);

    // lane-local inclusive prefix
    const float p0 = x0;
    const float p1 = p0 + x1;
    const float p2 = p1 + x2;
    const float p3 = p2 + x3;

    // 16-lane inclusive scan of per-lane sums (pure VALU via DPP; row_shr
    // stays within 16-lane DPP rows so segments are independent).
    float sc = p3;
    sc = dpp_shr_add<0x111>(sc);   // row_shr:1
    sc = dpp_shr_add<0x112>(sc);   // row_shr:2
    sc = dpp_shr_add<0x114>(sc);   // row_shr:4
    sc = dpp_shr_add<0x118>(sc);   // row_shr:8

    const float total = __shfl(sc, 15, 16);   // segment total (softmax denom)
    const float excl  = sc - p3;
    const float rtot  = __builtin_amdgcn_rcpf(total);
    const float er    = excl * rtot;

    // analytic cumsum of target_dist (softmax of +-10 logits)
    const float s = 2.0611536224385579e-9f;   // exp(-20)
    const float k  = (ee == 1) ? 1.0f : (float)(NBINS - tt);
    const float hi = __builtin_amdgcn_rcpf(k + (64.0f - k) * s);
    const float lo = s * hi;

    float acc = 0.0f;
    #pragma unroll
    for (int c = 0; c < 4; ++c) {
        const int j = j0 + c;
        const float p = (c == 0) ? p0 : (c == 1) ? p1 : (c == 2) ? p2 : p3;
        const float ones = (j >= tt) ? ((ee == 1) ? 1.0f : (float)(j - tt + 1))
                                     : 0.0f;
        const float cts = ones * hi + ((float)(j + 1) - ones) * lo;
        const float cps = fmaf(p, rtot, er);   // (excl + p) / total
        const float d = cps - cts;
        acc = fmaf(d, d, acc);
    }
    return valid ? acc : 0.0f;
}

#define QUADS_PER_WAVE 8

__global__ __launch_bounds__(256) void survemd_kernel(
    const float* __restrict__ y_hat,
    const int* __restrict__ t,
    const int* __restrict__ e,
    float* __restrict__ out,
    int n_rows)
{
    const int lane = threadIdx.x & 63;
    const int wave_in_block = threadIdx.x >> 6;
    const int waves_per_block = blockDim.x >> 6;
    const int wave_id = blockIdx.x * waves_per_block + wave_in_block;

    const int seg = lane >> 4;
    const int sl  = lane & 15;
    const float4* yv = (const float4*)y_hat;

    // Each wave owns 8 consecutive quads = 32 consecutive rows (8 KiB y_hat).
    const int base_quad = wave_id * QUADS_PER_WAVE;

    // ---- load phase: issue ALL global loads before any compute (MLP=8) ----
    float4 y[QUADS_PER_WAVE];
    int    tt[QUADS_PER_WAVE];
    int    ee[QUADS_PER_WAVE];
    bool   valid[QUADS_PER_WAVE];
    #pragma unroll
    for (int u = 0; u < QUADS_PER_WAVE; ++u) {
        const int row = (base_quad + u) * 4 + seg;
        const bool v = row < n_rows;
        const int crow = v ? row : (n_rows - 1);
        y[u]  = yv[(size_t)crow * (NBINS / 4) + sl];
        tt[u] = t[crow];
        ee[u] = e[crow];
        valid[u] = v;
    }

    // ---- compute phase: staged vmcnt waits overlap compute with loads ----
    float acc = 0.0f;
    #pragma unroll
    for (int u = 0; u < QUADS_PER_WAVE; ++u)
        acc += quad_compute(y[u], tt[u], ee[u], sl, valid[u]);

    // wave reduction
    #pragma unroll
    for (int off = 32; off >= 1; off >>= 1)
        acc += __shfl_down(acc, off, 64);

    __shared__ float wave_sums[8];
    if (lane == 0) wave_sums[wave_in_block] = acc;
    __syncthreads();
    if (threadIdx.x == 0) {
        float bsum = 0.0f;
        for (int w = 0; w < waves_per_block; ++w) bsum += wave_sums[w];
        atomicAdd(out, bsum * (1.0f / (float)n_rows));
    }
}

extern "C" void kernel_launch(void* const* d_in, const int* in_sizes, int n_in,
                              void* d_out, int out_size, void* d_ws, size_t ws_size,
                              hipStream_t stream) {
    const float* y_hat = (const float*)d_in[0];
    const int*   t     = (const int*)d_in[1];
    const int*   e     = (const int*)d_in[2];
    float* out = (float*)d_out;

    const int n_rows = in_sizes[1];  // B

    (void)hipMemsetAsync(out, 0, out_size * sizeof(float), stream);

    const int nquads = (n_rows + 3) >> 2;
    const int waves  = (nquads + QUADS_PER_WAVE - 1) / QUADS_PER_WAVE;
    const int block  = 256;                    // 4 waves/block
    const int grid   = (waves + 3) / 4;        // B=1M -> 8192 blocks
    survemd_kernel<<<grid, block, 0, stream>>>(y_hat, t, e, out, n_rows);
}

// Round 5
// 374.347 us; speedup vs baseline: 1.1755x; 1.0287x over previous
//
#include <hip/hip_runtime.h>

#define NBINS 64
#define QPC 4   // quads per chunk (chunk = 16 rows = 4 KiB of y_hat)

// DPP row_shr:N add within 16-lane rows, 0-fill (bound_ctrl=1) -> scan step.
template <int CTRL>
__device__ __forceinline__ float dpp_shr_add(float x) {
    int xi = __float_as_int(x);
    int sh = __builtin_amdgcn_update_dpp(0, xi, CTRL, 0xF, 0xF, true);
    return x + __int_as_float(sh);
}

struct Chunk {
    float4 y[QPC];
    int    t[QPC];
    int    e[QPC];
};

__device__ __forceinline__ void load_chunk(Chunk& c,
                                           const float4* __restrict__ yv,
                                           const int* __restrict__ t,
                                           const int* __restrict__ e,
                                           int chunk, int seg, int sl,
                                           int n_rows) {
    #pragma unroll
    for (int u = 0; u < QPC; ++u) {
        const int row = (chunk * QPC + u) * 4 + seg;
        const int crow = min(row, n_rows - 1);   // clamp; invalid zeroed later
        c.y[u] = yv[(size_t)crow * (NBINS / 4) + sl];
        c.t[u] = t[crow];
        c.e[u] = e[crow];
    }
}

__device__ __forceinline__ float compute_chunk(const Chunk& c, int chunk,
                                               int seg, int sl, int n_rows) {
    const int j0 = sl * 4;
    float acc = 0.0f;
    #pragma unroll
    for (int u = 0; u < QPC; ++u) {
        const int row = (chunk * QPC + u) * 4 + seg;
        const int tt = c.t[u];
        const int ee = c.e[u];
        const float4 y = c.y[u];

        // pred: e==1 -> y ; e==0 -> (j>=t ? 10 : y). exp safe without max-sub
        // (pred <= 10, row sum <= 64*e^10 ~ 1.4e6 : fine in fp32).
        const bool cen = (ee == 0);
        const float x0 = __expf((cen && (j0 + 0 >= tt)) ? 10.0f : y.x);
        const float x1 = __expf((cen && (j0 + 1 >= tt)) ? 10.0f : y.y);
        const float x2 = __expf((cen && (j0 + 2 >= tt)) ? 10.0f : y.z);
        const float x3 = __expf((cen && (j0 + 3 >= tt)) ? 10.0f : y.w);

        // lane-local inclusive prefix
        const float p0 = x0;
        const float p1 = p0 + x1;
        const float p2 = p1 + x2;
        const float p3 = p2 + x3;

        // 16-lane segmented inclusive scan (pure VALU via DPP row_shr)
        float sc = p3;
        sc = dpp_shr_add<0x111>(sc);
        sc = dpp_shr_add<0x112>(sc);
        sc = dpp_shr_add<0x114>(sc);
        sc = dpp_shr_add<0x118>(sc);

        const float total = __shfl(sc, 15, 16);   // segment total
        const float excl  = sc - p3;
        const float rtot  = __builtin_amdgcn_rcpf(total);
        const float er    = excl * rtot;

        // target cumsum, linear-in-j form:
        // cts(j) = (j+1)*lo + m(j);  m = 0 for j<t;
        //   e==1: m = hi-lo;  e==0: m = (j+1-t)*(hi-lo) = j*hl + (1-t)*hl
        const float s = 2.0611536224385579e-9f;   // exp(-20)
        const float k  = (ee == 1) ? 1.0f : (float)(NBINS - tt);
        const float hi = __builtin_amdgcn_rcpf(k + (64.0f - k) * s);
        const float lo = s * hi;
        const float hl = hi - lo;
        const float slope = cen ? hl : 0.0f;
        const float off   = cen ? (float)(1 - tt) * hl : hl;

        float q = 0.0f;
        #pragma unroll
        for (int cc = 0; cc < 4; ++cc) {
            const int j = j0 + cc;
            const float p = (cc == 0) ? p0 : (cc == 1) ? p1
                          : (cc == 2) ? p2 : p3;
            const float m   = (j >= tt) ? fmaf((float)j, slope, off) : 0.0f;
            const float cts = fmaf((float)(j + 1), lo, m);
            const float d   = fmaf(p, rtot, er - cts);   // cps - cts
            q = fmaf(d, d, q);
        }
        acc += (row < n_rows) ? q : 0.0f;
    }
    return acc;
}

__global__ __launch_bounds__(256, 4) void survemd_kernel(
    const float* __restrict__ y_hat,
    const int* __restrict__ t,
    const int* __restrict__ e,
    float* __restrict__ out,
    int n_rows)
{
    const int lane = threadIdx.x & 63;
    const int wave_in_block = threadIdx.x >> 6;
    const int waves_per_block = blockDim.x >> 6;
    const int wave_id = blockIdx.x * waves_per_block + wave_in_block;
    const int total_waves = gridDim.x * waves_per_block;

    const int seg = lane >> 4;
    const int sl  = lane & 15;
    const float4* yv = (const float4*)y_hat;

    const int nquads  = (n_rows + 3) >> 2;
    const int nchunks = (nquads + QPC - 1) / QPC;
    const int cpw     = (nchunks + total_waves - 1) / total_waves;

    // each wave owns a CONTIGUOUS span of chunks -> sequential streaming
    const int begin = wave_id * cpw;
    const int end   = min(begin + cpw, nchunks);

    float acc = 0.0f;
    if (begin < end) {
        Chunk A;
        load_chunk(A, yv, t, e, begin, seg, sl, n_rows);
        for (int i = begin; i < end; ++i) {
            Chunk B;
            const int nxt = (i + 1 < end) ? i + 1 : i;   // harmless reload
            load_chunk(B, yv, t, e, nxt, seg, sl, n_rows);   // prefetch
            acc += compute_chunk(A, i, seg, sl, n_rows);     // overlap
            A = B;
        }
    }

    // wave reduction
    #pragma unroll
    for (int off = 32; off >= 1; off >>= 1)
        acc += __shfl_down(acc, off, 64);

    __shared__ float wave_sums[8];
    if (lane == 0) wave_sums[wave_in_block] = acc;
    __syncthreads();
    if (threadIdx.x == 0) {
        float bsum = 0.0f;
        for (int w = 0; w < waves_per_block; ++w) bsum += wave_sums[w];
        atomicAdd(out, bsum * (1.0f / (float)n_rows));
    }
}

extern "C" void kernel_launch(void* const* d_in, const int* in_sizes, int n_in,
                              void* d_out, int out_size, void* d_ws, size_t ws_size,
                              hipStream_t stream) {
    const float* y_hat = (const float*)d_in[0];
    const int*   t     = (const int*)d_in[1];
    const int*   e     = (const int*)d_in[2];
    float* out = (float*)d_out;

    const int n_rows = in_sizes[1];  // B

    (void)hipMemsetAsync(out, 0, out_size * sizeof(float), stream);

    const int block = 256;   // 4 waves/block
    const int grid  = 2048;  // 8192 waves -> 8 chunk-iterations each at B=1M
    survemd_kernel<<<grid, block, 0, stream>>>(y_hat, t, e, out, n_rows);
}

// Round 6
// 363.356 us; speedup vs baseline: 1.2110x; 1.0302x over previous
//
#include <hip/hip_runtime.h>

#define NBINS 64

// quad_perm DPP: pure-VALU cross-lane within each 4-lane quad.
// CTRL = k|k<<2|k<<4|k<<6 broadcasts lane k of the quad.
template <int CTRL>
__device__ __forceinline__ float qperm(float x) {
    return __int_as_float(__builtin_amdgcn_update_dpp(
        0, __float_as_int(x), CTRL, 0xF, 0xF, true));
}

struct Group {            // one group = 16 rows; lane l owns row (l>>2),
    float4 y[4];          // bins [(l&3)*16 .. +15] as 4 float4s
    int    t, e;
};

__device__ __forceinline__ void load_group(Group& g,
                                           const float4* __restrict__ yv,
                                           const int* __restrict__ t,
                                           const int* __restrict__ e,
                                           int grp, int lane, int n_rows) {
    // flat float4 index: grp*1024/4 + lane*4 + c  (contiguous 4KiB per group)
    const size_t base = (size_t)grp * (16 * NBINS / 4) + lane * 4;
    #pragma unroll
    for (int c = 0; c < 4; ++c) g.y[c] = yv[base + c];
    const int row = grp * 16 + (lane >> 2);
    const int crow = min(row, n_rows - 1);
    g.t = t[crow];
    g.e = e[crow];
}

__device__ __forceinline__ float compute_group(const Group& g, int grp,
                                               int lane, float m1, float m2,
                                               float m3, int n_rows) {
    const int li = lane & 3;
    const int j0 = li * 16;           // first bin this lane owns
    const int tt = g.t;
    const int ee = g.e;
    const bool cen = (ee == 0);
    const float E10 = 22026.465794806718f;   // exp(10)

    // exp(pred): pred = (e==0 && j>=t) ? 10 : y  -> select OUTPUT (keeps
    // cmp/cndmask off the exp critical path). Safe without max-subtraction.
    float p[16];
    #pragma unroll
    for (int c = 0; c < 4; ++c) {
        const float4 y = g.y[c];
        #pragma unroll
        for (int k = 0; k < 4; ++k) {
            const int idx = c * 4 + k;
            const float yy = (k == 0) ? y.x : (k == 1) ? y.y
                           : (k == 2) ? y.z : y.w;
            const float ex = __expf(yy);
            const bool force = cen && (j0 + idx >= tt);
            p[idx] = force ? E10 : ex;
        }
    }
    // lane-local inclusive prefix over 16 elements (15 VALU adds, 16 rows/wave)
    #pragma unroll
    for (int idx = 1; idx < 16; ++idx) p[idx] += p[idx - 1];
    const float L = p[15];            // lane-local sum

    // cross-lane over the 4-lane quad: pure VALU (quad_perm broadcasts)
    const float b0 = qperm<0x00>(L);
    const float b1 = qperm<0x55>(L);
    const float b2 = qperm<0xAA>(L);
    const float b3 = qperm<0xFF>(L);
    const float excl  = fmaf(m1, b0, fmaf(m2, b1, m3 * b2));
    const float total = (b0 + b1) + (b2 + b3);
    const float rtot  = __builtin_amdgcn_rcpf(total);
    const float er    = excl * rtot;

    // analytic cumsum of target_dist (softmax of +-10 logits), linear in j:
    // cts(j) = (j+1)*lo + ((j>=t) ? j*slope + off : 0)
    const float s = 2.0611536224385579e-9f;   // exp(-20)
    const float k  = (ee == 1) ? 1.0f : (float)(NBINS - tt);
    const float hi = __builtin_amdgcn_rcpf(k + (64.0f - k) * s);
    const float lo = s * hi;
    const float hl = hi - lo;
    const float slope = cen ? hl : 0.0f;
    const float off   = cen ? (float)(1 - tt) * hl : hl;

    float acc = 0.0f;
    #pragma unroll
    for (int idx = 0; idx < 16; ++idx) {
        const int j = j0 + idx;
        const float m   = (j >= tt) ? fmaf((float)j, slope, off) : 0.0f;
        const float cts = fmaf((float)(j + 1), lo, m);
        const float d   = fmaf(p[idx], rtot, er - cts);   // cps - cts
        acc = fmaf(d, d, acc);
    }
    const int row = grp * 16 + (lane >> 2);
    return (row < n_rows) ? acc : 0.0f;
}

__global__ __launch_bounds__(256, 4) void survemd_kernel(
    const float* __restrict__ y_hat,
    const int* __restrict__ t,
    const int* __restrict__ e,
    float* __restrict__ out,
    int n_rows)
{
    const int lane = threadIdx.x & 63;
    const int wave_in_block = threadIdx.x >> 6;
    const int waves_per_block = blockDim.x >> 6;
    const int wave_id = blockIdx.x * waves_per_block + wave_in_block;
    const int total_waves = gridDim.x * waves_per_block;

    const float4* yv = (const float4*)y_hat;
    const int li = lane & 3;
    const float m1 = (li >= 1) ? 1.0f : 0.0f;
    const float m2 = (li >= 2) ? 1.0f : 0.0f;
    const float m3 = (li >= 3) ? 1.0f : 0.0f;

    const int ngroups = (n_rows + 15) >> 4;
    const int gpw     = (ngroups + total_waves - 1) / total_waves;
    const int begin   = wave_id * gpw;
    const int end     = min(begin + gpw, ngroups);

    float acc = 0.0f;
    if (begin < end) {
        Group A;
        load_group(A, yv, t, e, begin, lane, n_rows);
        for (int i = begin; i < end; ++i) {
            Group B;
            const int nxt = (i + 1 < end) ? i + 1 : i;
            load_group(B, yv, t, e, nxt, lane, n_rows);          // prefetch
            acc += compute_group(A, i, lane, m1, m2, m3, n_rows); // overlap
            A = B;
        }
    }

    // wave reduction
    #pragma unroll
    for (int off = 32; off >= 1; off >>= 1)
        acc += __shfl_down(acc, off, 64);

    __shared__ float wave_sums[8];
    if (lane == 0) wave_sums[wave_in_block] = acc;
    __syncthreads();
    if (threadIdx.x == 0) {
        float bsum = 0.0f;
        for (int w = 0; w < waves_per_block; ++w) bsum += wave_sums[w];
        atomicAdd(out, bsum * (1.0f / (float)n_rows));
    }
}

extern "C" void kernel_launch(void* const* d_in, const int* in_sizes, int n_in,
                              void* d_out, int out_size, void* d_ws, size_t ws_size,
                              hipStream_t stream) {
    const float* y_hat = (const float*)d_in[0];
    const int*   t     = (const int*)d_in[1];
    const int*   e     = (const int*)d_in[2];
    float* out = (float*)d_out;

    const int n_rows = in_sizes[1];  // B

    (void)hipMemsetAsync(out, 0, out_size * sizeof(float), stream);

    const int block = 256;   // 4 waves/block
    const int grid  = 2048;  // 8192 waves; B=1M -> 8 groups (128 rows) each
    survemd_kernel<<<grid, block, 0, stream>>>(y_hat, t, e, out, n_rows);
}